// Round 7
// baseline (220.559 us; speedup 1.0000x reference)
//
#include <hip/hip_runtime.h>

// Problem constants
#define BSZ   32
#define SEQ   4096
#define FDIM  512
#define KTOP  4
#define FK    128                 // FDIM / KTOP
#define MTOT  (BSZ * SEQ)         // 131072 GEMM rows
#define NCHUNK 32                 // 4096 / 128 seq-chunks per batch

// 256x256 GEMM tile geometry
#define BM2  256
#define BN2  256
#define BK2  64
#define NKT  (FDIM / BK2)         // 8 K-tiles

typedef __attribute__((ext_vector_type(8))) short bf16x8;
typedef __attribute__((ext_vector_type(4))) float f32x4;
typedef __attribute__((ext_vector_type(8))) unsigned short u16x8;

typedef __attribute__((address_space(1))) void void_g;
typedef __attribute__((address_space(3))) void void_l;

static __device__ __forceinline__ void load_lds16(const void* g, void* l) {
  __builtin_amdgcn_global_load_lds((void_g*)g, (void_l*)l, 16, 0, 0);
}

static __device__ __forceinline__ unsigned short f2bf(float f) {
  unsigned int u = __float_as_uint(f);
  unsigned int r = (u + 0x7fffu + ((u >> 16) & 1u)) >> 16;  // RNE
  return (unsigned short)r;
}

// ---- sorting-network helpers (descending) ----
static __device__ __forceinline__ void sort2(float& a, float& b) {
  float mx = fmaxf(a, b), mn = fminf(a, b); a = mx; b = mn;
}
static __device__ __forceinline__ void sort4(float& a, float& b, float& c, float& d) {
  sort2(a, b); sort2(c, d); sort2(a, c); sort2(b, d); sort2(b, c);
}
// merge two descending sorted-4 lists, keep top-4 descending in a..d
static __device__ __forceinline__ void merge4(float& a, float& b, float& c, float& d,
                                              float e, float f, float g, float h) {
  float m0 = fmaxf(a, h), m1 = fmaxf(b, g), m2 = fmaxf(c, f), m3 = fmaxf(d, e);
  sort2(m0, m2); sort2(m1, m3); sort2(m0, m1); sort2(m2, m3);
  a = m0; b = m1; c = m2; d = m3;
}

// ------------------------------------------------- Wu [k][n] f32 -> WuT [n][k] bf16
__global__ __launch_bounds__(256) void cvt_wuT_kernel(const float* __restrict__ Wu,
                                                      unsigned short* __restrict__ WuT) {
  int nn = blockIdx.x;  // 0..511
  for (int k = threadIdx.x; k < FDIM; k += blockDim.x)
    WuT[(size_t)nn * FDIM + k] = f2bf(Wu[(size_t)k * FDIM + nn]);
}

// ------------------------------------------------------------------- R precompute
// R[g][q] = sum_m P2[g][m] * Q[(g%4)*128 + m][q],  P2 = P.reshape(512,128)
__global__ __launch_bounds__(256) void compute_R_kernel(const float* __restrict__ P,
                                                        const float* __restrict__ Q,
                                                        float* __restrict__ R) {
  int g = blockIdx.y;                        // 0..511
  int q = blockIdx.x * 256 + threadIdx.x;    // 0..511
  __shared__ float p2[FK];
  if (threadIdx.x < FK) p2[threadIdx.x] = P[(size_t)g * FK + threadIdx.x];
  __syncthreads();
  const float* Qb = Q + (size_t)((g & 3) * FK) * FDIM + q;
  float s = 0.f;
#pragma unroll 8
  for (int m = 0; m < FK; ++m) s = fmaf(p2[m], Qb[(size_t)m * FDIM], s);
  R[(size_t)g * FDIM + q] = s;
}

// ------- 256x256 pipelined GEMM (A = f32 x, converted in-flight) + fused top-4
// X [MTOT][512] f32, Bt [n][k] bf16. Output: cand[b][f][chunk][4] f32 (sorted desc)
// 8 waves (2M x 4N). A: reg-staged, one register set. launch_bounds(512,1):
// the unified VGPR+AGPR budget must hold acc(128 AGPR) + frags(48) + in-flight
// A loads(32) — the (512,2) cap of 256 forced scratch spills (r5: 420 MB, r6:
// 172 MB WRITE_SIZE). Per tile kt: stage B(kt+1) -> AWRITE A(kt+1) -> issue
// A(kt+2) loads -> COMPUTE(cur) -> vmcnt(8) (A loads stay in flight) +
// lgkmcnt(0) + one s_barrier.
__global__ __launch_bounds__(512, 1) void gemm_topk_kernel(
    const float* __restrict__ X, const unsigned short* __restrict__ Bt,
    float* __restrict__ cand) {
  __shared__ __align__(16) unsigned short As[2][BM2 * BK2];  // 2 x 32 KB
  __shared__ __align__(16) unsigned short Bs[2][BM2 * BK2];  // 2 x 32 KB

  const int tid = threadIdx.x;
  const int lane = tid & 63;
  const int w = tid >> 6;                 // 0..7
  const int wm = w & 1, wn = w >> 1;      // 2 x 4 wave grid

  // XCD-grouped mapping: both n-tiles of one m-tile land adjacent on one XCD.
  const int xcd = blockIdx.x & 7;
  const int jj = blockIdx.x >> 3;         // 0..127
  const int t = xcd * 128 + jj;           // 0..1023
  const int mtile = t >> 1, ntile = t & 1;
  const int m0 = mtile * BM2, n0 = ntile * BN2;

  // ---- A staging (f32 source, reg roundtrip, swizzled ds_write) ----
  const int arow = tid >> 3;
  const int asc = tid & 7;
  const int aswz = (arow & 7) << 4;
  const float* axp[4];
  int aldst[4];
#pragma unroll
  for (int i = 0; i < 4; ++i) {
    const int row = i * 64 + arow;
    axp[i] = X + (size_t)(m0 + row) * FDIM + asc * 8;
    aldst[i] = row * 128 + ((asc * 16) ^ aswz);
  }
  float4 arA[4][2];

#define ALOADS(kt)                                                             \
  {                                                                            \
    _Pragma("unroll") for (int i = 0; i < 4; ++i) {                            \
      const float4* p = (const float4*)(axp[i] + (kt) * BK2);                  \
      arA[i][0] = p[0];                                                        \
      arA[i][1] = p[1];                                                        \
    }                                                                          \
  }

#define AWRITES(buf)                                                           \
  {                                                                            \
    _Pragma("unroll") for (int i = 0; i < 4; ++i) {                            \
      u16x8 o;                                                                 \
      o[0] = f2bf(arA[i][0].x); o[1] = f2bf(arA[i][0].y);                      \
      o[2] = f2bf(arA[i][0].z); o[3] = f2bf(arA[i][0].w);                      \
      o[4] = f2bf(arA[i][1].x); o[5] = f2bf(arA[i][1].y);                      \
      o[6] = f2bf(arA[i][1].z); o[7] = f2bf(arA[i][1].w);                      \
      *(u16x8*)((char*)As[buf] + aldst[i]) = o;                                \
    }                                                                          \
  }

  // ---- B staging: gload_lds, linear dest + inverse-swizzled source ----
  const char* bsrc[4];
#pragma unroll
  for (int i = 0; i < 4; ++i) {
    int o = i * 8192 + tid * 16;
    int row = o >> 7;
    int colb = (o & 127) ^ ((row & 7) << 4);
    bsrc[i] = (const char*)(Bt + (size_t)(n0 + row) * FDIM) + colb;
  }
  const int ldst = (tid >> 6) * 512;      // shorts; wave-uniform base

#define STAGE_B(kt, buf)                                                       \
  {                                                                            \
    _Pragma("unroll") for (int i = 0; i < 4; ++i)                              \
        load_lds16(bsrc[i] + (kt) * 128, (void*)(&Bs[buf][i * 4096 + ldst]));  \
  }

  // ---- fragment read offsets (swizzled) ----
  const int lr = lane & 15;
  const int g16 = lane >> 4;              // 0..3
  const int swz = (lr & 7) << 4;
  const int arow0 = (wm * 128 + lr) * 128;
  const int brow0 = (wn * 64 + lr) * 128;

  f32x4 acc[8][4];
#pragma unroll
  for (int mi = 0; mi < 8; ++mi)
#pragma unroll
    for (int ni = 0; ni < 4; ++ni) acc[mi][ni] = {0.f, 0.f, 0.f, 0.f};

#define COMPUTE(b)                                                             \
  {                                                                            \
    const char* Ap = (const char*)As[b];                                       \
    const char* Bp = (const char*)Bs[b];                                       \
    _Pragma("unroll") for (int kk = 0; kk < 2; ++kk) {                         \
      bf16x8 af[8], bfr[4];                                                    \
      const int kcol = kk * 64;                                                \
      _Pragma("unroll") for (int mi = 0; mi < 8; ++mi)                         \
          af[mi] = *(const bf16x8*)(Ap + arow0 + mi * 2048 +                   \
                                    ((kcol + g16 * 16) ^ swz));                \
      _Pragma("unroll") for (int ni = 0; ni < 4; ++ni)                         \
          bfr[ni] = *(const bf16x8*)(Bp + brow0 + ni * 2048 +                  \
                                     ((kcol + g16 * 16) ^ swz));               \
      __builtin_amdgcn_s_setprio(1);                                           \
      _Pragma("unroll") for (int mi = 0; mi < 8; ++mi)                         \
          _Pragma("unroll") for (int ni = 0; ni < 4; ++ni)                     \
              acc[mi][ni] = __builtin_amdgcn_mfma_f32_16x16x32_bf16(           \
                  af[mi], bfr[ni], acc[mi][ni], 0, 0, 0);                      \
      __builtin_amdgcn_s_setprio(0);                                           \
    }                                                                          \
  }

#define WAIT_BAR(n)                                                            \
  asm volatile("s_waitcnt vmcnt(" #n ") lgkmcnt(0)" ::: "memory");             \
  __builtin_amdgcn_s_barrier();                                                \
  __builtin_amdgcn_sched_barrier(0);

  // ---- prologue: tile 0 staged, A(1) loads in flight ----
  ALOADS(0);
  AWRITES(0);          // compiler vmcnt-waits arA's loads
  STAGE_B(0, 0);       // 4 gloads
  ALOADS(1);           // 8 loads, stay in flight across the barrier
  __builtin_amdgcn_sched_barrier(0);
  WAIT_BAR(8);         // drains B(0); leaves A(1)'s 8

  // ---- main loop: 1 barrier + 1 counted vmcnt per tile ----
#pragma unroll 1
  for (int ktp = 0; ktp < 4; ++ktp) {
    // even kt = 2*ktp, cur=0, nbuf=1
    {
      const int kt = 2 * ktp;
      STAGE_B(kt + 1, 1);            // always: kt+1 <= 7
      AWRITES(1);                    // A(kt+1) -> As[1]; loads a full tile old
      if (kt + 2 < NKT) {
        ALOADS(kt + 2);
        __builtin_amdgcn_sched_barrier(0);
      }
      COMPUTE(0);
      if (kt + 2 < NKT) { WAIT_BAR(8); } else { WAIT_BAR(0); }
    }
    // odd kt = 2*ktp+1, cur=1, nbuf=0
    {
      const int kt = 2 * ktp + 1;
      if (kt + 1 < NKT) {
        STAGE_B(kt + 1, 0);
        AWRITES(0);                  // A(kt+1) -> As[0]
        if (kt + 2 < NKT) {
          ALOADS(kt + 2);
          __builtin_amdgcn_sched_barrier(0);
        }
      }
      COMPUTE(1);
      if (kt + 1 < NKT) {
        if (kt + 2 < NKT) { WAIT_BAR(8); } else { WAIT_BAR(0); }
      }
    }
  }

  // ---- fused top-4: each wave owns one 128-row chunk (wm), cols wn*64..+63 ----
  const int mchunk = mtile * 2 + wm;      // global 128-row chunk id
  const int b = mchunk >> 5;
  const int chunk = mchunk & 31;
#pragma unroll
  for (int ni = 0; ni < 4; ++ni) {
    float a0 = acc[0][ni][0], a1 = acc[0][ni][1], a2 = acc[0][ni][2], a3 = acc[0][ni][3];
    sort4(a0, a1, a2, a3);
#pragma unroll
    for (int mi = 1; mi < 8; ++mi) {
      float b0 = acc[mi][ni][0], b1 = acc[mi][ni][1];
      float b2 = acc[mi][ni][2], b3 = acc[mi][ni][3];
      sort4(b0, b1, b2, b3);
      merge4(a0, a1, a2, a3, b0, b1, b2, b3);
    }
#pragma unroll
    for (int off = 16; off < 64; off <<= 1) {
      float e0 = __shfl_xor(a0, off), e1 = __shfl_xor(a1, off);
      float e2 = __shfl_xor(a2, off), e3 = __shfl_xor(a3, off);
      merge4(a0, a1, a2, a3, e0, e1, e2, e3);
    }
    if (lane < 16) {
      const int f = n0 + wn * 64 + ni * 16 + lane;
      float4 v; v.x = a0; v.y = a1; v.z = a2; v.w = a3;
      *(float4*)(cand + (((size_t)(b * FDIM + f)) * NCHUNK + chunk) * 4) = v;
    }
  }
}

// ---------------------- merge 32 chunk-lists + 4-term contraction + relu -> out
// one wave per output row (b,ff); 4 rows per block
__global__ __launch_bounds__(256) void out_kernel(
    const float* __restrict__ cand, const float* __restrict__ R,
    const float* __restrict__ Bb, float* __restrict__ out) {
  const int row = blockIdx.x * 4 + (threadIdx.x >> 6);  // b*512 + ff
  const int lane = threadIdx.x & 63;
  const int b = row >> 9, ff = row & 511;
  const int m2 = ff & 127;

  const float4 cv = *(const float4*)(cand +
      (((size_t)(b * FDIM + ff)) * NCHUNK + (lane & 31)) * 4);
  float t0 = cv.x, t1 = cv.y, t2 = cv.z, t3 = cv.w;
#pragma unroll
  for (int off = 1; off < 32; off <<= 1) {
    float e0 = __shfl_xor(t0, off), e1 = __shfl_xor(t1, off);
    float e2 = __shfl_xor(t2, off), e3 = __shfl_xor(t3, off);
    merge4(t0, t1, t2, t3, e0, e1, e2, e3);
  }
  t0 = fmaxf(t0, 0.f); t1 = fmaxf(t1, 0.f); t2 = fmaxf(t2, 0.f); t3 = fmaxf(t3, 0.f);

  const float* R0 = R + (size_t)(4 * m2) * FDIM;
  const float* Bbr = Bb + (size_t)m2 * FDIM;
  float* ob = out + (size_t)row * FDIM;
#pragma unroll
  for (int jq = 0; jq < 8; ++jq) {
    const int q = jq * 64 + lane;
    float s = Bbr[q];
    s = fmaf(t0, R0[q], s);
    s = fmaf(t1, R0[FDIM + q], s);
    s = fmaf(t2, R0[2 * FDIM + q], s);
    s = fmaf(t3, R0[3 * FDIM + q], s);
    ob[q] = s > 0.f ? s : 0.f;
  }
}

// ---------------------------------------------------------------------------------
extern "C" void kernel_launch(void* const* d_in, const int* in_sizes, int n_in,
                              void* d_out, int out_size, void* d_ws, size_t ws_size,
                              hipStream_t stream) {
  const float* x  = (const float*)d_in[0];
  const float* Wu = (const float*)d_in[1];
  const float* P  = (const float*)d_in[2];
  const float* Q  = (const float*)d_in[3];
  const float* Bb = (const float*)d_in[4];
  float* out = (float*)d_out;

  char* ws = (char*)d_ws;
  unsigned short* wuT = (unsigned short*)(ws);          //  524288 B
  float*          R   = (float*)(ws + 524288L);         // 1048576 B
  float*          cand= (float*)(ws + 1572864L);        // 8388608 B

  hipLaunchKernelGGL(cvt_wuT_kernel, dim3(512), dim3(256), 0, stream, Wu, wuT);
  hipLaunchKernelGGL(compute_R_kernel, dim3(2, 512), dim3(256), 0, stream, P, Q, R);
  hipLaunchKernelGGL(gemm_topk_kernel, dim3(1024), dim3(512), 0, stream, x, wuT, cand);
  hipLaunchKernelGGL(out_kernel, dim3(BSZ * FDIM / 4), dim3(256), 0, stream, cand, R, Bb, out);
}

// Round 8
// 162.196 us; speedup vs baseline: 1.3598x; 1.3598x over previous
//
#include <hip/hip_runtime.h>

// Problem constants
#define BSZ   32
#define SEQ   4096
#define FDIM  512
#define KTOP  4
#define FK    128                 // FDIM / KTOP
#define MTOT  (BSZ * SEQ)         // 131072 GEMM rows
#define NCHUNK 32                 // 4096 / 128 seq-chunks per batch

// 128x128 GEMM tile geometry (fits reg-staged f32 A: acc=64 AGPR, ~115 VGPR)
#define BM2  128
#define BN2  128
#define BK2  64
#define NKT  (FDIM / BK2)         // 8 K-tiles

typedef __attribute__((ext_vector_type(8))) short bf16x8;
typedef __attribute__((ext_vector_type(4))) float f32x4;
typedef __attribute__((ext_vector_type(8))) unsigned short u16x8;

typedef __attribute__((address_space(1))) void void_g;
typedef __attribute__((address_space(3))) void void_l;

static __device__ __forceinline__ void load_lds16(const void* g, void* l) {
  __builtin_amdgcn_global_load_lds((void_g*)g, (void_l*)l, 16, 0, 0);
}

static __device__ __forceinline__ unsigned short f2bf(float f) {
  unsigned int u = __float_as_uint(f);
  unsigned int r = (u + 0x7fffu + ((u >> 16) & 1u)) >> 16;  // RNE
  return (unsigned short)r;
}

// ---- sorting-network helpers (descending) ----
static __device__ __forceinline__ void sort2(float& a, float& b) {
  float mx = fmaxf(a, b), mn = fminf(a, b); a = mx; b = mn;
}
static __device__ __forceinline__ void sort4(float& a, float& b, float& c, float& d) {
  sort2(a, b); sort2(c, d); sort2(a, c); sort2(b, d); sort2(b, c);
}
// merge two descending sorted-4 lists, keep top-4 descending in a..d
static __device__ __forceinline__ void merge4(float& a, float& b, float& c, float& d,
                                              float e, float f, float g, float h) {
  float m0 = fmaxf(a, h), m1 = fmaxf(b, g), m2 = fmaxf(c, f), m3 = fmaxf(d, e);
  sort2(m0, m2); sort2(m1, m3); sort2(m0, m1); sort2(m2, m3);
  a = m0; b = m1; c = m2; d = m3;
}

// ------------------------------------------------- Wu [k][n] f32 -> WuT [n][k] bf16
__global__ __launch_bounds__(256) void cvt_wuT_kernel(const float* __restrict__ Wu,
                                                      unsigned short* __restrict__ WuT) {
  int nn = blockIdx.x;  // 0..511
  for (int k = threadIdx.x; k < FDIM; k += blockDim.x)
    WuT[(size_t)nn * FDIM + k] = f2bf(Wu[(size_t)k * FDIM + nn]);
}

// ------------------------------------------------------------------- R precompute
// R[g][q] = sum_m P2[g][m] * Q[(g%4)*128 + m][q],  P2 = P.reshape(512,128)
__global__ __launch_bounds__(256) void compute_R_kernel(const float* __restrict__ P,
                                                        const float* __restrict__ Q,
                                                        float* __restrict__ R) {
  int g = blockIdx.y;                        // 0..511
  int q = blockIdx.x * 256 + threadIdx.x;    // 0..511
  __shared__ float p2[FK];
  if (threadIdx.x < FK) p2[threadIdx.x] = P[(size_t)g * FK + threadIdx.x];
  __syncthreads();
  const float* Qb = Q + (size_t)((g & 3) * FK) * FDIM + q;
  float s = 0.f;
#pragma unroll 8
  for (int m = 0; m < FK; ++m) s = fmaf(p2[m], Qb[(size_t)m * FDIM], s);
  R[(size_t)g * FDIM + q] = s;
}

// ------- 128x128 pipelined GEMM (A = f32 x, converted in-flight) + fused top-4
// X [MTOT][512] f32, Bt [n][k] bf16. Output: cand[b][f][chunk][4] f32 (sorted desc)
// 4 waves (2M x 2N), per-wave 64x64, acc = 64 AGPR. A: reg-staged f32->bf16 with
// swizzled ds_write; B: gload_lds with inverse-swizzled source. Counted vmcnt:
// per tile, stage B(kt+1) -> AWRITE A(kt+1) -> issue A(kt+2) -> COMPUTE ->
// vmcnt(8) (A loads stay in flight) + lgkmcnt(0) + one s_barrier.
// 68 KB LDS -> 2 blocks/CU (8 waves/CU TLP).
__global__ __launch_bounds__(256, 2) void gemm_topk_kernel(
    const float* __restrict__ X, const unsigned short* __restrict__ Bt,
    float* __restrict__ cand) {
  __shared__ __align__(16) unsigned short As[2][BM2 * BK2];  // 2 x 16 KB
  __shared__ __align__(16) unsigned short Bs[2][BN2 * BK2];  // 2 x 16 KB
  __shared__ float4 tl[BN2 * 2];                             // [col][wm] 4 KB

  const int tid = threadIdx.x;
  const int lane = tid & 63;
  const int w = tid >> 6;                 // 0..3
  const int wm = w & 1, wn = w >> 1;      // 2 x 2 wave grid

  // XCD-grouped mapping: the 4 n-tiles of one m-tile land adjacent on one XCD.
  const int xcd = blockIdx.x & 7;
  const int jj = blockIdx.x >> 3;         // 0..511
  const int t = xcd * 512 + jj;           // 0..4095
  const int mt = t >> 2, nt = t & 3;      // 1024 m-tiles x 4 n-tiles
  const int m0 = mt * BM2, n0 = nt * BN2;

  // ---- A staging (f32 source, reg roundtrip, swizzled ds_write) ----
  // i-chunk: row = i*32 + (tid>>3), col-16B-slot = tid&7
  const int arow = tid >> 3;              // 0..31
  const int asc = tid & 7;
  const int aswz = (arow & 7) << 4;       // i*32 ≡ 0 mod 8
  const float* axp[4];
  int aldst[4];
#pragma unroll
  for (int i = 0; i < 4; ++i) {
    const int row = i * 32 + arow;
    axp[i] = X + (size_t)(m0 + row) * FDIM + asc * 8;
    aldst[i] = row * 128 + ((asc * 16) ^ aswz);
  }
  float4 arA[4][2];

#define ALOADS(kt)                                                             \
  {                                                                            \
    _Pragma("unroll") for (int i = 0; i < 4; ++i) {                            \
      const float4* p = (const float4*)(axp[i] + (kt) * BK2);                  \
      arA[i][0] = p[0];                                                        \
      arA[i][1] = p[1];                                                        \
    }                                                                          \
  }

#define AWRITES(buf)                                                           \
  {                                                                            \
    _Pragma("unroll") for (int i = 0; i < 4; ++i) {                            \
      u16x8 o;                                                                 \
      o[0] = f2bf(arA[i][0].x); o[1] = f2bf(arA[i][0].y);                      \
      o[2] = f2bf(arA[i][0].z); o[3] = f2bf(arA[i][0].w);                      \
      o[4] = f2bf(arA[i][1].x); o[5] = f2bf(arA[i][1].y);                      \
      o[6] = f2bf(arA[i][1].z); o[7] = f2bf(arA[i][1].w);                      \
      *(u16x8*)((char*)As[buf] + aldst[i]) = o;                                \
    }                                                                          \
  }

  // ---- B staging: gload_lds, linear dest + inverse-swizzled source ----
  const char* bsrc[4];
#pragma unroll
  for (int i = 0; i < 4; ++i) {
    int o = i * 4096 + tid * 16;          // byte offset in 16KB tile
    int row = o >> 7;                     // 0..127
    int colb = (o & 127) ^ ((row & 7) << 4);
    bsrc[i] = (const char*)(Bt + (size_t)(n0 + row) * FDIM) + colb;
  }
  const int ldst = (tid >> 6) * 512;      // shorts; wave-uniform base

#define STAGE_B(kt, buf)                                                       \
  {                                                                            \
    _Pragma("unroll") for (int i = 0; i < 4; ++i)                              \
        load_lds16(bsrc[i] + (kt) * 128, (void*)(&Bs[buf][i * 2048 + ldst]));  \
  }

  // ---- fragment read offsets (swizzled) ----
  const int lr = lane & 15;
  const int g16 = lane >> 4;              // 0..3
  const int swz = (lr & 7) << 4;
  const int arow0 = (wm * 64 + lr) * 128;
  const int brow0 = (wn * 64 + lr) * 128;

  f32x4 acc[4][4];
#pragma unroll
  for (int mi = 0; mi < 4; ++mi)
#pragma unroll
    for (int ni = 0; ni < 4; ++ni) acc[mi][ni] = {0.f, 0.f, 0.f, 0.f};

#define COMPUTE(b)                                                             \
  {                                                                            \
    const char* Ap = (const char*)As[b];                                       \
    const char* Bp = (const char*)Bs[b];                                       \
    _Pragma("unroll") for (int kk = 0; kk < 2; ++kk) {                         \
      bf16x8 af[4], bfr[4];                                                    \
      const int kcol = kk * 64;                                                \
      _Pragma("unroll") for (int mi = 0; mi < 4; ++mi)                         \
          af[mi] = *(const bf16x8*)(Ap + arow0 + mi * 2048 +                   \
                                    ((kcol + g16 * 16) ^ swz));                \
      _Pragma("unroll") for (int ni = 0; ni < 4; ++ni)                         \
          bfr[ni] = *(const bf16x8*)(Bp + brow0 + ni * 2048 +                  \
                                     ((kcol + g16 * 16) ^ swz));               \
      __builtin_amdgcn_s_setprio(1);                                           \
      _Pragma("unroll") for (int mi = 0; mi < 4; ++mi)                         \
          _Pragma("unroll") for (int ni = 0; ni < 4; ++ni)                     \
              acc[mi][ni] = __builtin_amdgcn_mfma_f32_16x16x32_bf16(           \
                  af[mi], bfr[ni], acc[mi][ni], 0, 0, 0);                      \
      __builtin_amdgcn_s_setprio(0);                                           \
    }                                                                          \
  }

#define WAIT_BAR(n)                                                            \
  asm volatile("s_waitcnt vmcnt(" #n ") lgkmcnt(0)" ::: "memory");             \
  __builtin_amdgcn_s_barrier();                                                \
  __builtin_amdgcn_sched_barrier(0);

  // ---- prologue: tile 0 staged, A(1) loads in flight ----
  ALOADS(0);
  AWRITES(0);          // compiler vmcnt-waits arA's loads
  STAGE_B(0, 0);       // 4 gloads
  ALOADS(1);           // 8 loads, stay in flight across the barrier
  __builtin_amdgcn_sched_barrier(0);
  WAIT_BAR(8);         // drains B(0); leaves A(1)'s 8

  // ---- main loop: 1 barrier + 1 counted vmcnt per tile ----
#pragma unroll 1
  for (int ktp = 0; ktp < 4; ++ktp) {
    // even kt = 2*ktp, cur=0, nbuf=1
    {
      const int kt = 2 * ktp;
      STAGE_B(kt + 1, 1);            // always: kt+1 <= 7
      AWRITES(1);                    // A(kt+1) -> As[1]; loads a full tile old
      if (kt + 2 < NKT) {
        ALOADS(kt + 2);
        __builtin_amdgcn_sched_barrier(0);
      }
      COMPUTE(0);
      if (kt + 2 < NKT) { WAIT_BAR(8); } else { WAIT_BAR(0); }
    }
    // odd kt = 2*ktp+1, cur=1, nbuf=0
    {
      const int kt = 2 * ktp + 1;
      if (kt + 1 < NKT) {
        STAGE_B(kt + 1, 0);
        AWRITES(0);                  // A(kt+1) -> As[0]
        if (kt + 2 < NKT) {
          ALOADS(kt + 2);
          __builtin_amdgcn_sched_barrier(0);
        }
      }
      COMPUTE(1);
      if (kt + 1 < NKT) {
        if (kt + 2 < NKT) { WAIT_BAR(8); } else { WAIT_BAR(0); }
      }
    }
  }

  // ---- fused top-4 per column over this tile's 128 rows ----
  // wave (wm) covers rows wm*64 + mi*16 + g16*4 + r; in-lane 16 values,
  // shfl over g16, cross-wm merge via tl.
#pragma unroll
  for (int ni = 0; ni < 4; ++ni) {
    float a0 = acc[0][ni][0], a1 = acc[0][ni][1], a2 = acc[0][ni][2], a3 = acc[0][ni][3];
    sort4(a0, a1, a2, a3);
#pragma unroll
    for (int mi = 1; mi < 4; ++mi) {
      float b0 = acc[mi][ni][0], b1 = acc[mi][ni][1];
      float b2 = acc[mi][ni][2], b3 = acc[mi][ni][3];
      sort4(b0, b1, b2, b3);
      merge4(a0, a1, a2, a3, b0, b1, b2, b3);
    }
#pragma unroll
    for (int off = 16; off < 64; off <<= 1) {
      float e0 = __shfl_xor(a0, off), e1 = __shfl_xor(a1, off);
      float e2 = __shfl_xor(a2, off), e3 = __shfl_xor(a3, off);
      merge4(a0, a1, a2, a3, e0, e1, e2, e3);
    }
    if (lane < 16) {
      float4 v; v.x = a0; v.y = a1; v.z = a2; v.w = a3;
      tl[(wn * 64 + ni * 16 + lane) * 2 + wm] = v;
    }
  }
  __syncthreads();

  if (tid < BN2) {
    const int col = tid;
    float4 u = tl[col * 2 + 0];
    float4 v = tl[col * 2 + 1];
    merge4(u.x, u.y, u.z, u.w, v.x, v.y, v.z, v.w);
    const int b = mt >> 5;          // 32 m-tiles (=chunks) per batch
    const int chunk = mt & 31;
    const int f = n0 + col;
    *(float4*)(cand + (((size_t)(b * FDIM + f)) * NCHUNK + chunk) * 4) = u;
  }
}

// ---------------------- merge 32 chunk-lists + 4-term contraction + relu -> out
// one wave per output row (b,ff); 4 rows per block
__global__ __launch_bounds__(256) void out_kernel(
    const float* __restrict__ cand, const float* __restrict__ R,
    const float* __restrict__ Bb, float* __restrict__ out) {
  const int row = blockIdx.x * 4 + (threadIdx.x >> 6);  // b*512 + ff
  const int lane = threadIdx.x & 63;
  const int b = row >> 9, ff = row & 511;
  const int m2 = ff & 127;

  const float4 cv = *(const float4*)(cand +
      (((size_t)(b * FDIM + ff)) * NCHUNK + (lane & 31)) * 4);
  float t0 = cv.x, t1 = cv.y, t2 = cv.z, t3 = cv.w;
#pragma unroll
  for (int off = 1; off < 32; off <<= 1) {
    float e0 = __shfl_xor(t0, off), e1 = __shfl_xor(t1, off);
    float e2 = __shfl_xor(t2, off), e3 = __shfl_xor(t3, off);
    merge4(t0, t1, t2, t3, e0, e1, e2, e3);
  }
  t0 = fmaxf(t0, 0.f); t1 = fmaxf(t1, 0.f); t2 = fmaxf(t2, 0.f); t3 = fmaxf(t3, 0.f);

  const float* R0 = R + (size_t)(4 * m2) * FDIM;
  const float* Bbr = Bb + (size_t)m2 * FDIM;
  float* ob = out + (size_t)row * FDIM;
#pragma unroll
  for (int jq = 0; jq < 8; ++jq) {
    const int q = jq * 64 + lane;
    float s = Bbr[q];
    s = fmaf(t0, R0[q], s);
    s = fmaf(t1, R0[FDIM + q], s);
    s = fmaf(t2, R0[2 * FDIM + q], s);
    s = fmaf(t3, R0[3 * FDIM + q], s);
    ob[q] = s > 0.f ? s : 0.f;
  }
}

// ---------------------------------------------------------------------------------
extern "C" void kernel_launch(void* const* d_in, const int* in_sizes, int n_in,
                              void* d_out, int out_size, void* d_ws, size_t ws_size,
                              hipStream_t stream) {
  const float* x  = (const float*)d_in[0];
  const float* Wu = (const float*)d_in[1];
  const float* P  = (const float*)d_in[2];
  const float* Q  = (const float*)d_in[3];
  const float* Bb = (const float*)d_in[4];
  float* out = (float*)d_out;

  char* ws = (char*)d_ws;
  unsigned short* wuT = (unsigned short*)(ws);          //  524288 B
  float*          R   = (float*)(ws + 524288L);         // 1048576 B
  float*          cand= (float*)(ws + 1572864L);        // 8388608 B

  hipLaunchKernelGGL(cvt_wuT_kernel, dim3(512), dim3(256), 0, stream, Wu, wuT);
  hipLaunchKernelGGL(compute_R_kernel, dim3(2, 512), dim3(256), 0, stream, P, Q, R);
  hipLaunchKernelGGL(gemm_topk_kernel, dim3(4096), dim3(256), 0, stream, x, wuT, cand);
  hipLaunchKernelGGL(out_kernel, dim3(BSZ * FDIM / 4), dim3(256), 0, stream, cand, R, Bb, out);
}

// Round 9
// 151.036 us; speedup vs baseline: 1.4603x; 1.0739x over previous
//
#include <hip/hip_runtime.h>

// Problem constants
#define BSZ   32
#define SEQ   4096
#define FDIM  512
#define KTOP  4
#define FK    128                 // FDIM / KTOP
#define MTOT  (BSZ * SEQ)         // 131072 GEMM rows
#define NCHUNK 32                 // 4096 / 128 seq-chunks per batch

// 256x256 GEMM tile geometry
#define BM2  256
#define BN2  256
#define BK2  64
#define NKT  (FDIM / BK2)         // 8 K-tiles

typedef __attribute__((ext_vector_type(8))) short bf16x8;
typedef __attribute__((ext_vector_type(4))) float f32x4;
typedef __attribute__((ext_vector_type(8))) unsigned short u16x8;

typedef __attribute__((address_space(1))) void void_g;
typedef __attribute__((address_space(3))) void void_l;

static __device__ __forceinline__ void load_lds16(const void* g, void* l) {
  __builtin_amdgcn_global_load_lds((void_g*)g, (void_l*)l, 16, 0, 0);
}

static __device__ __forceinline__ unsigned short f2bf(float f) {
  unsigned int u = __float_as_uint(f);
  unsigned int r = (u + 0x7fffu + ((u >> 16) & 1u)) >> 16;  // RNE
  return (unsigned short)r;
}

// ---- sorting-network helpers (descending) ----
static __device__ __forceinline__ void sort2(float& a, float& b) {
  float mx = fmaxf(a, b), mn = fminf(a, b); a = mx; b = mn;
}
static __device__ __forceinline__ void sort4(float& a, float& b, float& c, float& d) {
  sort2(a, b); sort2(c, d); sort2(a, c); sort2(b, d); sort2(b, c);
}
// merge two descending sorted-4 lists, keep top-4 descending in a..d
static __device__ __forceinline__ void merge4(float& a, float& b, float& c, float& d,
                                              float e, float f, float g, float h) {
  float m0 = fmaxf(a, h), m1 = fmaxf(b, g), m2 = fmaxf(c, f), m3 = fmaxf(d, e);
  sort2(m0, m2); sort2(m1, m3); sort2(m0, m1); sort2(m2, m3);
  a = m0; b = m1; c = m2; d = m3;
}

// ------------------------------------------------- Wu [k][n] f32 -> WuT [n][k] bf16
__global__ __launch_bounds__(256) void cvt_wuT_kernel(const float* __restrict__ Wu,
                                                      unsigned short* __restrict__ WuT) {
  int nn = blockIdx.x;  // 0..511
  for (int k = threadIdx.x; k < FDIM; k += blockDim.x)
    WuT[(size_t)nn * FDIM + k] = f2bf(Wu[(size_t)k * FDIM + nn]);
}

// ------------------------------------------------------------------- R precompute
// R[g][q] = sum_m P2[g][m] * Q[(g%4)*128 + m][q],  P2 = P.reshape(512,128)
__global__ __launch_bounds__(256) void compute_R_kernel(const float* __restrict__ P,
                                                        const float* __restrict__ Q,
                                                        float* __restrict__ R) {
  int g = blockIdx.y;                        // 0..511
  int q = blockIdx.x * 256 + threadIdx.x;    // 0..511
  __shared__ float p2[FK];
  if (threadIdx.x < FK) p2[threadIdx.x] = P[(size_t)g * FK + threadIdx.x];
  __syncthreads();
  const float* Qb = Q + (size_t)((g & 3) * FK) * FDIM + q;
  float s = 0.f;
#pragma unroll 8
  for (int m = 0; m < FK; ++m) s = fmaf(p2[m], Qb[(size_t)m * FDIM], s);
  R[(size_t)g * FDIM + q] = s;
}

// ------- 256x256 8-PHASE pipelined GEMM (A = f32 x, cvt in-flight) + fused top-4
// X [MTOT][512] f32, Bt [n][k] bf16. Output: cand[b][f][chunk][4] f32 (sorted desc)
// 8 waves (2M x 4N), per-wave 128x64, acc = 128 AGPR. m201-style schedule:
// per K-tile, 4 phases; each phase = {12 ds_read (one C-quadrant) | one staging
// piece -> s_barrier -> setprio(1) -> 16 MFMA -> setprio(0) -> s_barrier}.
// ph0: issue A(kt+1) f32 loads (3 phases slack). ph1: B(kt+1) gload_lds.
// ph3: AWRITE (cvt f32->bf16, swizzled ds_write) + boundary vmcnt(0)+lgkm(0).
// LDS = 128 KB exactly (no tl buffer; per-wave top-4 chunk epilogue).
__global__ __launch_bounds__(512, 1) void gemm_topk_kernel(
    const float* __restrict__ X, const unsigned short* __restrict__ Bt,
    float* __restrict__ cand) {
  __shared__ __align__(16) unsigned short As[2][BM2 * BK2];  // 2 x 32 KB
  __shared__ __align__(16) unsigned short Bs[2][BM2 * BK2];  // 2 x 32 KB

  const int tid = threadIdx.x;
  const int lane = tid & 63;
  const int w = tid >> 6;                 // 0..7
  const int wm = w & 1, wn = w >> 1;      // 2 x 4 wave grid

  // XCD-grouped mapping: both n-tiles of one m-tile land adjacent on one XCD.
  const int xcd = blockIdx.x & 7;
  const int jj = blockIdx.x >> 3;         // 0..127
  const int t = xcd * 128 + jj;           // 0..1023
  const int mtile = t >> 1, ntile = t & 1;
  const int m0 = mtile * BM2, n0 = ntile * BN2;

  // ---- A staging (f32 source, reg roundtrip, swizzled ds_write) ----
  const int arow = tid >> 3;              // 0..63
  const int asc = tid & 7;
  const int aswz = (arow & 7) << 4;       // i*64 ≡ 0 mod 8
  const float* axp[4];
  int aldst[4];
#pragma unroll
  for (int i = 0; i < 4; ++i) {
    const int row = i * 64 + arow;
    axp[i] = X + (size_t)(m0 + row) * FDIM + asc * 8;
    aldst[i] = row * 128 + ((asc * 16) ^ aswz);
  }
  float4 arA[4][2];

#define ALOADS(kt)                                                             \
  {                                                                            \
    _Pragma("unroll") for (int i = 0; i < 4; ++i) {                            \
      const float4* p = (const float4*)(axp[i] + (kt) * BK2);                  \
      arA[i][0] = p[0];                                                        \
      arA[i][1] = p[1];                                                        \
    }                                                                          \
  }

#define AWRITES(buf)                                                           \
  {                                                                            \
    _Pragma("unroll") for (int i = 0; i < 4; ++i) {                            \
      u16x8 o;                                                                 \
      o[0] = f2bf(arA[i][0].x); o[1] = f2bf(arA[i][0].y);                      \
      o[2] = f2bf(arA[i][0].z); o[3] = f2bf(arA[i][0].w);                      \
      o[4] = f2bf(arA[i][1].x); o[5] = f2bf(arA[i][1].y);                      \
      o[6] = f2bf(arA[i][1].z); o[7] = f2bf(arA[i][1].w);                      \
      *(u16x8*)((char*)As[buf] + aldst[i]) = o;                                \
    }                                                                          \
  }

  // ---- B staging: gload_lds, linear dest + inverse-swizzled source ----
  const char* bsrc[4];
#pragma unroll
  for (int i = 0; i < 4; ++i) {
    int o = i * 8192 + tid * 16;
    int row = o >> 7;
    int colb = (o & 127) ^ ((row & 7) << 4);
    bsrc[i] = (const char*)(Bt + (size_t)(n0 + row) * FDIM) + colb;
  }
  const int ldst = (tid >> 6) * 512;      // shorts; wave-uniform base

#define STAGE_B(kt, buf)                                                       \
  {                                                                            \
    _Pragma("unroll") for (int i = 0; i < 4; ++i)                              \
        load_lds16(bsrc[i] + (kt) * 128, (void*)(&Bs[buf][i * 4096 + ldst]));  \
  }

  // ---- fragment read offsets (swizzled) ----
  const int lr = lane & 15;
  const int g16 = lane >> 4;              // 0..3
  const int swz = (lr & 7) << 4;
  const int arow0 = (wm * 128 + lr) * 128;
  const int brow0 = (wn * 64 + lr) * 128;

  f32x4 acc[8][4];
#pragma unroll
  for (int mi = 0; mi < 8; ++mi)
#pragma unroll
    for (int ni = 0; ni < 4; ++ni) acc[mi][ni] = {0.f, 0.f, 0.f, 0.f};

  // One phase: quadrant (mh in 0..1 -> 4 mi, nh in 0..1 -> 2 ni), both kk.
  // 12 ds_read_b128 + STAGE code -> barrier -> 16 MFMA (setprio) -> barrier.
#define PHASE(Ap, Bp, mh, nh, ...)                                             \
  {                                                                            \
    bf16x8 af[4][2], bfr[2][2];                                                \
    _Pragma("unroll") for (int j = 0; j < 4; ++j)                              \
        _Pragma("unroll") for (int kq = 0; kq < 2; ++kq)                       \
            af[j][kq] = *(const bf16x8*)((Ap) + arow0 + ((mh)*4 + j) * 2048 +  \
                                         ((kq * 64 + g16 * 16) ^ swz));        \
    _Pragma("unroll") for (int j = 0; j < 2; ++j)                              \
        _Pragma("unroll") for (int kq = 0; kq < 2; ++kq)                       \
            bfr[j][kq] = *(const bf16x8*)((Bp) + brow0 + ((nh)*2 + j) * 2048 + \
                                          ((kq * 64 + g16 * 16) ^ swz));       \
    __VA_ARGS__;                                                               \
    __builtin_amdgcn_s_barrier();                                              \
    __builtin_amdgcn_s_setprio(1);                                             \
    _Pragma("unroll") for (int j = 0; j < 4; ++j)                              \
        _Pragma("unroll") for (int jn = 0; jn < 2; ++jn)                       \
            _Pragma("unroll") for (int kq = 0; kq < 2; ++kq)                   \
                acc[(mh)*4 + j][(nh)*2 + jn] =                                 \
                    __builtin_amdgcn_mfma_f32_16x16x32_bf16(                   \
                        af[j][kq], bfr[jn][kq], acc[(mh)*4 + j][(nh)*2 + jn],  \
                        0, 0, 0);                                              \
    __builtin_amdgcn_s_setprio(0);                                             \
  }

  // ---- prologue: tile 0 fully staged ----
  ALOADS(0);
  AWRITES(0);                    // compiler vmcnt-waits arA's loads
  STAGE_B(0, 0);                 // 4 gloads
  asm volatile("s_waitcnt vmcnt(0) lgkmcnt(0)" ::: "memory");
  __builtin_amdgcn_s_barrier();
  __builtin_amdgcn_sched_barrier(0);

  // ---- main loop: 4 phases per K-tile ----
#pragma unroll 1
  for (int kt = 0; kt < NKT; ++kt) {
    const int c = kt & 1;
    const char* Ap = (const char*)As[c];
    const char* Bp = (const char*)Bs[c];
    const int last = (kt == NKT - 1);

    // ph0: issue next A loads (3 phases of slack before AWRITE)
    PHASE(Ap, Bp, 0, 0, if (!last) ALOADS(kt + 1));
    __builtin_amdgcn_s_barrier();
    // ph1: issue next B gload_lds
    PHASE(Ap, Bp, 0, 1, if (!last) STAGE_B(kt + 1, c ^ 1));
    __builtin_amdgcn_s_barrier();
    // ph2: pure compute
    PHASE(Ap, Bp, 1, 0, );
    __builtin_amdgcn_s_barrier();
    // ph3: AWRITE next A (vmcnt wait covered by ph1+ph2), then boundary drain
    PHASE(Ap, Bp, 1, 1, if (!last) AWRITES(c ^ 1));
    asm volatile("s_waitcnt vmcnt(0) lgkmcnt(0)" ::: "memory");
    __builtin_amdgcn_s_barrier();
    __builtin_amdgcn_sched_barrier(0);
  }

  // ---- fused top-4: each wave owns one 128-row chunk (wm), cols wn*64..+63 ----
  const int mchunk = mtile * 2 + wm;      // global 128-row chunk id
  const int b = mchunk >> 5;
  const int chunk = mchunk & 31;
#pragma unroll
  for (int ni = 0; ni < 4; ++ni) {
    float a0 = acc[0][ni][0], a1 = acc[0][ni][1], a2 = acc[0][ni][2], a3 = acc[0][ni][3];
    sort4(a0, a1, a2, a3);
#pragma unroll
    for (int mi = 1; mi < 8; ++mi) {
      float b0 = acc[mi][ni][0], b1 = acc[mi][ni][1];
      float b2 = acc[mi][ni][2], b3 = acc[mi][ni][3];
      sort4(b0, b1, b2, b3);
      merge4(a0, a1, a2, a3, b0, b1, b2, b3);
    }
#pragma unroll
    for (int off = 16; off < 64; off <<= 1) {
      float e0 = __shfl_xor(a0, off), e1 = __shfl_xor(a1, off);
      float e2 = __shfl_xor(a2, off), e3 = __shfl_xor(a3, off);
      merge4(a0, a1, a2, a3, e0, e1, e2, e3);
    }
    if (lane < 16) {
      const int f = n0 + wn * 64 + ni * 16 + lane;
      float4 v; v.x = a0; v.y = a1; v.z = a2; v.w = a3;
      *(float4*)(cand + (((size_t)(b * FDIM + f)) * NCHUNK + chunk) * 4) = v;
    }
  }
}

// ---------------------- merge 32 chunk-lists + 4-term contraction + relu -> out
// one wave per output row (b,ff); 4 rows per block
__global__ __launch_bounds__(256) void out_kernel(
    const float* __restrict__ cand, const float* __restrict__ R,
    const float* __restrict__ Bb, float* __restrict__ out) {
  const int row = blockIdx.x * 4 + (threadIdx.x >> 6);  // b*512 + ff
  const int lane = threadIdx.x & 63;
  const int b = row >> 9, ff = row & 511;
  const int m2 = ff & 127;

  const float4 cv = *(const float4*)(cand +
      (((size_t)(b * FDIM + ff)) * NCHUNK + (lane & 31)) * 4);
  float t0 = cv.x, t1 = cv.y, t2 = cv.z, t3 = cv.w;
#pragma unroll
  for (int off = 1; off < 32; off <<= 1) {
    float e0 = __shfl_xor(t0, off), e1 = __shfl_xor(t1, off);
    float e2 = __shfl_xor(t2, off), e3 = __shfl_xor(t3, off);
    merge4(t0, t1, t2, t3, e0, e1, e2, e3);
  }
  t0 = fmaxf(t0, 0.f); t1 = fmaxf(t1, 0.f); t2 = fmaxf(t2, 0.f); t3 = fmaxf(t3, 0.f);

  const float* R0 = R + (size_t)(4 * m2) * FDIM;
  const float* Bbr = Bb + (size_t)m2 * FDIM;
  float* ob = out + (size_t)row * FDIM;
#pragma unroll
  for (int jq = 0; jq < 8; ++jq) {
    const int q = jq * 64 + lane;
    float s = Bbr[q];
    s = fmaf(t0, R0[q], s);
    s = fmaf(t1, R0[FDIM + q], s);
    s = fmaf(t2, R0[2 * FDIM + q], s);
    s = fmaf(t3, R0[3 * FDIM + q], s);
    ob[q] = s > 0.f ? s : 0.f;
  }
}

// ---------------------------------------------------------------------------------
extern "C" void kernel_launch(void* const* d_in, const int* in_sizes, int n_in,
                              void* d_out, int out_size, void* d_ws, size_t ws_size,
                              hipStream_t stream) {
  const float* x  = (const float*)d_in[0];
  const float* Wu = (const float*)d_in[1];
  const float* P  = (const float*)d_in[2];
  const float* Q  = (const float*)d_in[3];
  const float* Bb = (const float*)d_in[4];
  float* out = (float*)d_out;

  char* ws = (char*)d_ws;
  unsigned short* wuT = (unsigned short*)(ws);          //  524288 B
  float*          R   = (float*)(ws + 524288L);         // 1048576 B
  float*          cand= (float*)(ws + 1572864L);        // 8388608 B

  hipLaunchKernelGGL(cvt_wuT_kernel, dim3(512), dim3(256), 0, stream, Wu, wuT);
  hipLaunchKernelGGL(compute_R_kernel, dim3(2, 512), dim3(256), 0, stream, P, Q, R);
  hipLaunchKernelGGL(gemm_topk_kernel, dim3(1024), dim3(512), 0, stream, x, wuT, cand);
  hipLaunchKernelGGL(out_kernel, dim3(BSZ * FDIM / 4), dim3(256), 0, stream, cand, R, Bb, out);
}

// Round 10
// 147.310 us; speedup vs baseline: 1.4972x; 1.0253x over previous
//
#include <hip/hip_runtime.h>

// Problem constants
#define BSZ   32
#define SEQ   4096
#define FDIM  512
#define KTOP  4
#define FK    128                 // FDIM / KTOP
#define MTOT  (BSZ * SEQ)         // 131072 GEMM rows
#define NCHUNK 32                 // 4096 / 128 seq-chunks per batch

// 256x256 GEMM tile geometry
#define BM2  256
#define BN2  256
#define BK2  64
#define NKT  (FDIM / BK2)         // 8 K-tiles

typedef __attribute__((ext_vector_type(8))) short bf16x8;
typedef __attribute__((ext_vector_type(4))) float f32x4;
typedef __attribute__((ext_vector_type(8))) unsigned short u16x8;

typedef __attribute__((address_space(1))) void void_g;
typedef __attribute__((address_space(3))) void void_l;

static __device__ __forceinline__ void load_lds16(const void* g, void* l) {
  __builtin_amdgcn_global_load_lds((void_g*)g, (void_l*)l, 16, 0, 0);
}

static __device__ __forceinline__ unsigned short f2bf(float f) {
  unsigned int u = __float_as_uint(f);
  unsigned int r = (u + 0x7fffu + ((u >> 16) & 1u)) >> 16;  // RNE
  return (unsigned short)r;
}

// ---- sorting-network helpers (descending) ----
static __device__ __forceinline__ void sort2(float& a, float& b) {
  float mx = fmaxf(a, b), mn = fminf(a, b); a = mx; b = mn;
}
static __device__ __forceinline__ void sort4(float& a, float& b, float& c, float& d) {
  sort2(a, b); sort2(c, d); sort2(a, c); sort2(b, d); sort2(b, c);
}
// merge two descending sorted-4 lists, keep top-4 descending in a..d
static __device__ __forceinline__ void merge4(float& a, float& b, float& c, float& d,
                                              float e, float f, float g, float h) {
  float m0 = fmaxf(a, h), m1 = fmaxf(b, g), m2 = fmaxf(c, f), m3 = fmaxf(d, e);
  sort2(m0, m2); sort2(m1, m3); sort2(m0, m1); sort2(m2, m3);
  a = m0; b = m1; c = m2; d = m3;
}

// ------------------------------------------------- Wu [k][n] f32 -> WuT [n][k] bf16
__global__ __launch_bounds__(256) void cvt_wuT_kernel(const float* __restrict__ Wu,
                                                      unsigned short* __restrict__ WuT) {
  int nn = blockIdx.x;  // 0..511
  for (int k = threadIdx.x; k < FDIM; k += blockDim.x)
    WuT[(size_t)nn * FDIM + k] = f2bf(Wu[(size_t)k * FDIM + nn]);
}

// ------------------------------------------------------------------- R precompute
// R[g][q] = sum_m P2[g][m] * Q[(g%4)*128 + m][q],  P2 = P.reshape(512,128)
__global__ __launch_bounds__(256) void compute_R_kernel(const float* __restrict__ P,
                                                        const float* __restrict__ Q,
                                                        float* __restrict__ R) {
  int g = blockIdx.y;                        // 0..511
  int q = blockIdx.x * 256 + threadIdx.x;    // 0..511
  __shared__ float p2[FK];
  if (threadIdx.x < FK) p2[threadIdx.x] = P[(size_t)g * FK + threadIdx.x];
  __syncthreads();
  const float* Qb = Q + (size_t)((g & 3) * FK) * FDIM + q;
  float s = 0.f;
#pragma unroll 8
  for (int m = 0; m < FK; ++m) s = fmaf(p2[m], Qb[(size_t)m * FDIM], s);
  R[(size_t)g * FDIM + q] = s;
}

// ------- 256x256 8-phase GEMM (A = f32 x, cvt in-flight) + fused top-4
// X [MTOT][512] f32, Bt [n][k] bf16. Output: cand[b][f][chunk][4] f32 (sorted desc)
// 8 waves (2M x 4N), per-wave 128x64, acc = 128 AGPR.
// Key fix vs r9: each fragment is ds_read ONCE per K-tile (24 b128/wave/K-tile,
// not 48) — bfr[4] persists in-register across a phase pair (m201's actual
// recipe: "4 or 8 ds_read per phase"). Phases per K-tile:
//   ph0 (kq0): read bfr[0..3]+af[0..3] (8) | ALOADS(kt+1)  -> MFMA mi0-3
//   ph1 (kq0): read af[4..7] (4)          | STAGE_B(kt+1)  -> MFMA mi4-7
//   ph2 (kq1): read bfr[0..3]+af[0..3] (8)                 -> MFMA mi0-3
//   ph3 (kq1): read af[4..7] (4)          | AWRITES + drain-> MFMA mi4-7
__global__ __launch_bounds__(512, 1) void gemm_topk_kernel(
    const float* __restrict__ X, const unsigned short* __restrict__ Bt,
    float* __restrict__ cand) {
  __shared__ __align__(16) unsigned short As[2][BM2 * BK2];  // 2 x 32 KB
  __shared__ __align__(16) unsigned short Bs[2][BM2 * BK2];  // 2 x 32 KB

  const int tid = threadIdx.x;
  const int lane = tid & 63;
  const int w = tid >> 6;                 // 0..7
  const int wm = w & 1, wn = w >> 1;      // 2 x 4 wave grid

  // XCD-grouped mapping: both n-tiles of one m-tile land adjacent on one XCD.
  const int xcd = blockIdx.x & 7;
  const int jj = blockIdx.x >> 3;         // 0..127
  const int t = xcd * 128 + jj;           // 0..1023
  const int mtile = t >> 1, ntile = t & 1;
  const int m0 = mtile * BM2, n0 = ntile * BN2;

  // ---- A staging (f32 source, reg roundtrip, swizzled ds_write) ----
  const int arow = tid >> 3;              // 0..63
  const int asc = tid & 7;
  const int aswz = (arow & 7) << 4;       // i*64 ≡ 0 mod 8
  const float* axp[4];
  int aldst[4];
#pragma unroll
  for (int i = 0; i < 4; ++i) {
    const int row = i * 64 + arow;
    axp[i] = X + (size_t)(m0 + row) * FDIM + asc * 8;
    aldst[i] = row * 128 + ((asc * 16) ^ aswz);
  }
  float4 arA[4][2];

#define ALOADS(kt)                                                             \
  {                                                                            \
    _Pragma("unroll") for (int i = 0; i < 4; ++i) {                            \
      const float4* p = (const float4*)(axp[i] + (kt) * BK2);                  \
      arA[i][0] = p[0];                                                        \
      arA[i][1] = p[1];                                                        \
    }                                                                          \
  }

#define AWRITES(buf)                                                           \
  {                                                                            \
    _Pragma("unroll") for (int i = 0; i < 4; ++i) {                            \
      u16x8 o;                                                                 \
      o[0] = f2bf(arA[i][0].x); o[1] = f2bf(arA[i][0].y);                      \
      o[2] = f2bf(arA[i][0].z); o[3] = f2bf(arA[i][0].w);                      \
      o[4] = f2bf(arA[i][1].x); o[5] = f2bf(arA[i][1].y);                      \
      o[6] = f2bf(arA[i][1].z); o[7] = f2bf(arA[i][1].w);                      \
      *(u16x8*)((char*)As[buf] + aldst[i]) = o;                                \
    }                                                                          \
  }

  // ---- B staging: gload_lds, linear dest + inverse-swizzled source ----
  const char* bsrc[4];
#pragma unroll
  for (int i = 0; i < 4; ++i) {
    int o = i * 8192 + tid * 16;
    int row = o >> 7;
    int colb = (o & 127) ^ ((row & 7) << 4);
    bsrc[i] = (const char*)(Bt + (size_t)(n0 + row) * FDIM) + colb;
  }
  const int ldst = (tid >> 6) * 512;      // shorts; wave-uniform base

#define STAGE_B(kt, buf)                                                       \
  {                                                                            \
    _Pragma("unroll") for (int i = 0; i < 4; ++i)                              \
        load_lds16(bsrc[i] + (kt) * 128, (void*)(&Bs[buf][i * 4096 + ldst]));  \
  }

  // ---- fragment read offsets (swizzled) ----
  const int lr = lane & 15;
  const int g16 = lane >> 4;              // 0..3
  const int swz = (lr & 7) << 4;
  const int arow0 = (wm * 128 + lr) * 128;
  const int brow0 = (wn * 64 + lr) * 128;

  f32x4 acc[8][4];
#pragma unroll
  for (int mi = 0; mi < 8; ++mi)
#pragma unroll
    for (int ni = 0; ni < 4; ++ni) acc[mi][ni] = {0.f, 0.f, 0.f, 0.f};

  // Phase A: read bfr[0..3][kq] + af[0..3][kq], MFMA mi 0-3 (16)
#define PHASE_A(Ap, Bp, kq, ...)                                               \
  {                                                                            \
    bf16x8 af[4];                                                              \
    _Pragma("unroll") for (int jn = 0; jn < 4; ++jn)                           \
        bfr[jn] = *(const bf16x8*)((Bp) + brow0 + jn * 2048 +                  \
                                   (((kq)*64 + g16 * 16) ^ swz));              \
    _Pragma("unroll") for (int j = 0; j < 4; ++j)                              \
        af[j] = *(const bf16x8*)((Ap) + arow0 + j * 2048 +                     \
                                 (((kq)*64 + g16 * 16) ^ swz));                \
    __VA_ARGS__;                                                               \
    __builtin_amdgcn_s_barrier();                                              \
    __builtin_amdgcn_s_setprio(1);                                             \
    _Pragma("unroll") for (int j = 0; j < 4; ++j)                              \
        _Pragma("unroll") for (int jn = 0; jn < 4; ++jn)                       \
            acc[j][jn] = __builtin_amdgcn_mfma_f32_16x16x32_bf16(              \
                af[j], bfr[jn], acc[j][jn], 0, 0, 0);                          \
    __builtin_amdgcn_s_setprio(0);                                             \
  }

  // Phase B: read af[4..7][kq] only (bfr reused in-register), MFMA mi 4-7 (16)
#define PHASE_B(Ap, kq, ...)                                                   \
  {                                                                            \
    bf16x8 af[4];                                                              \
    _Pragma("unroll") for (int j = 0; j < 4; ++j)                              \
        af[j] = *(const bf16x8*)((Ap) + arow0 + (4 + j) * 2048 +               \
                                 (((kq)*64 + g16 * 16) ^ swz));                \
    __VA_ARGS__;                                                               \
    __builtin_amdgcn_s_barrier();                                              \
    __builtin_amdgcn_s_setprio(1);                                             \
    _Pragma("unroll") for (int j = 0; j < 4; ++j)                              \
        _Pragma("unroll") for (int jn = 0; jn < 4; ++jn)                       \
            acc[4 + j][jn] = __builtin_amdgcn_mfma_f32_16x16x32_bf16(          \
                af[j], bfr[jn], acc[4 + j][jn], 0, 0, 0);                      \
    __builtin_amdgcn_s_setprio(0);                                             \
  }

  // ---- prologue: tile 0 fully staged ----
  ALOADS(0);
  AWRITES(0);                    // compiler vmcnt-waits arA's loads
  STAGE_B(0, 0);                 // 4 gloads
  asm volatile("s_waitcnt vmcnt(0) lgkmcnt(0)" ::: "memory");
  __builtin_amdgcn_s_barrier();
  __builtin_amdgcn_sched_barrier(0);

  // ---- main loop: 4 phases per K-tile, each fragment read once ----
#pragma unroll 1
  for (int kt = 0; kt < NKT; ++kt) {
    const int c = kt & 1;
    const char* Ap = (const char*)As[c];
    const char* Bp = (const char*)Bs[c];
    const int last = (kt == NKT - 1);
    bf16x8 bfr[4];

    // ph0: kq0, full reads | issue next A f32 loads (3 phases of slack)
    PHASE_A(Ap, Bp, 0, if (!last) ALOADS(kt + 1));
    __builtin_amdgcn_s_barrier();
    // ph1: kq0, af only | issue next B gload_lds
    PHASE_B(Ap, 0, if (!last) STAGE_B(kt + 1, c ^ 1));
    __builtin_amdgcn_s_barrier();
    // ph2: kq1, full reads
    PHASE_A(Ap, Bp, 1, );
    __builtin_amdgcn_s_barrier();
    // ph3: kq1, af only | AWRITE next A (vmcnt covered by ph1+ph2)
    PHASE_B(Ap, 1, if (!last) AWRITES(c ^ 1));
    asm volatile("s_waitcnt vmcnt(0) lgkmcnt(0)" ::: "memory");
    __builtin_amdgcn_s_barrier();
    __builtin_amdgcn_sched_barrier(0);
  }

  // ---- fused top-4: each wave owns one 128-row chunk (wm), cols wn*64..+63 ----
  const int mchunk = mtile * 2 + wm;      // global 128-row chunk id
  const int b = mchunk >> 5;
  const int chunk = mchunk & 31;
#pragma unroll
  for (int ni = 0; ni < 4; ++ni) {
    float a0 = acc[0][ni][0], a1 = acc[0][ni][1], a2 = acc[0][ni][2], a3 = acc[0][ni][3];
    sort4(a0, a1, a2, a3);
#pragma unroll
    for (int mi = 1; mi < 8; ++mi) {
      float b0 = acc[mi][ni][0], b1 = acc[mi][ni][1];
      float b2 = acc[mi][ni][2], b3 = acc[mi][ni][3];
      sort4(b0, b1, b2, b3);
      merge4(a0, a1, a2, a3, b0, b1, b2, b3);
    }
#pragma unroll
    for (int off = 16; off < 64; off <<= 1) {
      float e0 = __shfl_xor(a0, off), e1 = __shfl_xor(a1, off);
      float e2 = __shfl_xor(a2, off), e3 = __shfl_xor(a3, off);
      merge4(a0, a1, a2, a3, e0, e1, e2, e3);
    }
    if (lane < 16) {
      const int f = n0 + wn * 64 + ni * 16 + lane;
      float4 v; v.x = a0; v.y = a1; v.z = a2; v.w = a3;
      *(float4*)(cand + (((size_t)(b * FDIM + f)) * NCHUNK + chunk) * 4) = v;
    }
  }
}

// ---------------------- merge 32 chunk-lists + 4-term contraction + relu -> out
// one wave per output row (b,ff); 4 rows per block
__global__ __launch_bounds__(256) void out_kernel(
    const float* __restrict__ cand, const float* __restrict__ R,
    const float* __restrict__ Bb, float* __restrict__ out) {
  const int row = blockIdx.x * 4 + (threadIdx.x >> 6);  // b*512 + ff
  const int lane = threadIdx.x & 63;
  const int b = row >> 9, ff = row & 511;
  const int m2 = ff & 127;

  const float4 cv = *(const float4*)(cand +
      (((size_t)(b * FDIM + ff)) * NCHUNK + (lane & 31)) * 4);
  float t0 = cv.x, t1 = cv.y, t2 = cv.z, t3 = cv.w;
#pragma unroll
  for (int off = 1; off < 32; off <<= 1) {
    float e0 = __shfl_xor(t0, off), e1 = __shfl_xor(t1, off);
    float e2 = __shfl_xor(t2, off), e3 = __shfl_xor(t3, off);
    merge4(t0, t1, t2, t3, e0, e1, e2, e3);
  }
  t0 = fmaxf(t0, 0.f); t1 = fmaxf(t1, 0.f); t2 = fmaxf(t2, 0.f); t3 = fmaxf(t3, 0.f);

  const float* R0 = R + (size_t)(4 * m2) * FDIM;
  const float* Bbr = Bb + (size_t)m2 * FDIM;
  float* ob = out + (size_t)row * FDIM;
#pragma unroll
  for (int jq = 0; jq < 8; ++jq) {
    const int q = jq * 64 + lane;
    float s = Bbr[q];
    s = fmaf(t0, R0[q], s);
    s = fmaf(t1, R0[FDIM + q], s);
    s = fmaf(t2, R0[2 * FDIM + q], s);
    s = fmaf(t3, R0[3 * FDIM + q], s);
    ob[q] = s > 0.f ? s : 0.f;
  }
}

// ---------------------------------------------------------------------------------
extern "C" void kernel_launch(void* const* d_in, const int* in_sizes, int n_in,
                              void* d_out, int out_size, void* d_ws, size_t ws_size,
                              hipStream_t stream) {
  const float* x  = (const float*)d_in[0];
  const float* Wu = (const float*)d_in[1];
  const float* P  = (const float*)d_in[2];
  const float* Q  = (const float*)d_in[3];
  const float* Bb = (const float*)d_in[4];
  float* out = (float*)d_out;

  char* ws = (char*)d_ws;
  unsigned short* wuT = (unsigned short*)(ws);          //  524288 B
  float*          R   = (float*)(ws + 524288L);         // 1048576 B
  float*          cand= (float*)(ws + 1572864L);        // 8388608 B

  hipLaunchKernelGGL(cvt_wuT_kernel, dim3(512), dim3(256), 0, stream, Wu, wuT);
  hipLaunchKernelGGL(compute_R_kernel, dim3(2, 512), dim3(256), 0, stream, P, Q, R);
  hipLaunchKernelGGL(gemm_topk_kernel, dim3(1024), dim3(512), 0, stream, x, wuT, cand);
  hipLaunchKernelGGL(out_kernel, dim3(BSZ * FDIM / 4), dim3(256), 0, stream, cand, R, Bb, out);
}

// Round 11
// 140.397 us; speedup vs baseline: 1.5710x; 1.0492x over previous
//
#include <hip/hip_runtime.h>

// Problem constants
#define BSZ   32
#define SEQ   4096
#define FDIM  512
#define KTOP  4
#define FK    128                 // FDIM / KTOP
#define MTOT  (BSZ * SEQ)         // 131072 GEMM rows
#define NCHUNK 32                 // 4096 / 128 seq-chunks per batch

// 256x256 GEMM tile geometry
#define BM2  256
#define BN2  256
#define BK2  64
#define NKT  (FDIM / BK2)         // 8 K-tiles

typedef __attribute__((ext_vector_type(8))) short bf16x8;
typedef __attribute__((ext_vector_type(4))) float f32x4;
typedef __attribute__((ext_vector_type(16))) float f32x16;
typedef __attribute__((ext_vector_type(8))) unsigned short u16x8;

typedef __attribute__((address_space(1))) void void_g;
typedef __attribute__((address_space(3))) void void_l;

static __device__ __forceinline__ void load_lds16(const void* g, void* l) {
  __builtin_amdgcn_global_load_lds((void_g*)g, (void_l*)l, 16, 0, 0);
}

static __device__ __forceinline__ unsigned short f2bf(float f) {
  unsigned int u = __float_as_uint(f);
  unsigned int r = (u + 0x7fffu + ((u >> 16) & 1u)) >> 16;  // RNE
  return (unsigned short)r;
}

// ---- sorting-network helpers (descending) ----
static __device__ __forceinline__ void sort2(float& a, float& b) {
  float mx = fmaxf(a, b), mn = fminf(a, b); a = mx; b = mn;
}
static __device__ __forceinline__ void sort4(float& a, float& b, float& c, float& d) {
  sort2(a, b); sort2(c, d); sort2(a, c); sort2(b, d); sort2(b, c);
}
// merge two descending sorted-4 lists, keep top-4 descending in a..d
static __device__ __forceinline__ void merge4(float& a, float& b, float& c, float& d,
                                              float e, float f, float g, float h) {
  float m0 = fmaxf(a, h), m1 = fmaxf(b, g), m2 = fmaxf(c, f), m3 = fmaxf(d, e);
  sort2(m0, m2); sort2(m1, m3); sort2(m0, m1); sort2(m2, m3);
  a = m0; b = m1; c = m2; d = m3;
}

// ------------------------------------------------- Wu [k][n] f32 -> WuT [n][k] bf16
__global__ __launch_bounds__(256) void cvt_wuT_kernel(const float* __restrict__ Wu,
                                                      unsigned short* __restrict__ WuT) {
  int nn = blockIdx.x;  // 0..511
  for (int k = threadIdx.x; k < FDIM; k += blockDim.x)
    WuT[(size_t)nn * FDIM + k] = f2bf(Wu[(size_t)k * FDIM + nn]);
}

// ------------------------------------------------------------------- R precompute
// R[g][q] = sum_m P2[g][m] * Q[(g%4)*128 + m][q],  P2 = P.reshape(512,128)
__global__ __launch_bounds__(256) void compute_R_kernel(const float* __restrict__ P,
                                                        const float* __restrict__ Q,
                                                        float* __restrict__ R) {
  int g = blockIdx.y;                        // 0..511
  int q = blockIdx.x * 256 + threadIdx.x;    // 0..511
  __shared__ float p2[FK];
  if (threadIdx.x < FK) p2[threadIdx.x] = P[(size_t)g * FK + threadIdx.x];
  __syncthreads();
  const float* Qb = Q + (size_t)((g & 3) * FK) * FDIM + q;
  float s = 0.f;
#pragma unroll 8
  for (int m = 0; m < FK; ++m) s = fmaf(p2[m], Qb[(size_t)m * FDIM], s);
  R[(size_t)g * FDIM + q] = s;
}

// ------- 256x256 GEMM on mfma_32x32x16 (A = f32 x, cvt in-flight) + fused top-4
// X [MTOT][512] f32, Bt [n][k] bf16. Output: cand[b][f][chunk][4] f32 (sorted desc)
// 8 waves (2M x 4N), per-wave 128x64 = 4x2 frags of 32x32, acc = 128 AGPR.
// 32x32x16 runs at 2382 TF (vs 2075 for 16x16x32) and HALVES the MFMA
// instruction count (32/wave/K-tile) — attacks the issue/sync-bound regime
// identified in r10. 2 phases per K-tile (4 barriers, was 8):
//   ph0: 12 ds_read (kq0,1) | STAGE_B(kt+1)                 -> 16 MFMA
//   ph1: 12 ds_read (kq2,3) | AWRITES(kt+1); ALOADS(kt+2)   -> 16 MFMA
//   boundary: vmcnt(8) (A(kt+2) stays in flight) + lgkmcnt(0) + s_barrier.
// Frag maps: A row=lane&31, B col=lane&31, k=8*(lane>>5)+j (same rule both
// operands); C/D col=lane&31, row=(reg&3)+8*(reg>>2)+4*(lane>>5) [HW-verified].
__global__ __launch_bounds__(512, 1) void gemm_topk_kernel(
    const float* __restrict__ X, const unsigned short* __restrict__ Bt,
    float* __restrict__ cand) {
  __shared__ __align__(16) unsigned short As[2][BM2 * BK2];  // 2 x 32 KB
  __shared__ __align__(16) unsigned short Bs[2][BM2 * BK2];  // 2 x 32 KB

  const int tid = threadIdx.x;
  const int lane = tid & 63;
  const int w = tid >> 6;                 // 0..7
  const int wm = w & 1, wn = w >> 1;      // 2 x 4 wave grid

  // XCD-grouped mapping: both n-tiles of one m-tile land adjacent on one XCD.
  const int xcd = blockIdx.x & 7;
  const int jj = blockIdx.x >> 3;         // 0..127
  const int t = xcd * 128 + jj;           // 0..1023
  const int mtile = t >> 1, ntile = t & 1;
  const int m0 = mtile * BM2, n0 = ntile * BN2;

  // ---- A staging (f32 source, reg roundtrip, swizzled ds_write) ----
  const int arow = tid >> 3;              // 0..63
  const int asc = tid & 7;
  const int aswz = (arow & 7) << 4;       // i*64 ≡ 0 mod 8
  const float* axp[4];
  int aldst[4];
#pragma unroll
  for (int i = 0; i < 4; ++i) {
    const int row = i * 64 + arow;
    axp[i] = X + (size_t)(m0 + row) * FDIM + asc * 8;
    aldst[i] = row * 128 + ((asc * 16) ^ aswz);
  }
  float4 arA[4][2];

#define ALOADS(kt)                                                             \
  {                                                                            \
    _Pragma("unroll") for (int i = 0; i < 4; ++i) {                            \
      const float4* p = (const float4*)(axp[i] + (kt) * BK2);                  \
      arA[i][0] = p[0];                                                        \
      arA[i][1] = p[1];                                                        \
    }                                                                          \
  }

#define AWRITES(buf)                                                           \
  {                                                                            \
    _Pragma("unroll") for (int i = 0; i < 4; ++i) {                            \
      u16x8 o;                                                                 \
      o[0] = f2bf(arA[i][0].x); o[1] = f2bf(arA[i][0].y);                      \
      o[2] = f2bf(arA[i][0].z); o[3] = f2bf(arA[i][0].w);                      \
      o[4] = f2bf(arA[i][1].x); o[5] = f2bf(arA[i][1].y);                      \
      o[6] = f2bf(arA[i][1].z); o[7] = f2bf(arA[i][1].w);                      \
      *(u16x8*)((char*)As[buf] + aldst[i]) = o;                                \
    }                                                                          \
  }

  // ---- B staging: gload_lds, linear dest + inverse-swizzled source ----
  const char* bsrc[4];
#pragma unroll
  for (int i = 0; i < 4; ++i) {
    int o = i * 8192 + tid * 16;
    int row = o >> 7;
    int colb = (o & 127) ^ ((row & 7) << 4);
    bsrc[i] = (const char*)(Bt + (size_t)(n0 + row) * FDIM) + colb;
  }
  const int ldst = (tid >> 6) * 512;      // shorts; wave-uniform base

#define STAGE_B(kt, buf)                                                       \
  {                                                                            \
    _Pragma("unroll") for (int i = 0; i < 4; ++i)                              \
        load_lds16(bsrc[i] + (kt) * 128, (void*)(&Bs[buf][i * 4096 + ldst]));  \
  }

  // ---- fragment read offsets (swizzled) ----
  const int l32 = lane & 31;
  const int g32 = lane >> 5;              // 0..1
  const int swz = (lane & 7) << 4;
  const int arow0 = (wm * 128 + l32) * 128;   // byte base of A frag row
  const int brow0 = (wn * 64 + l32) * 128;    // byte base of B frag row

  f32x16 acc[4][2];
#pragma unroll
  for (int mi = 0; mi < 4; ++mi)
#pragma unroll
    for (int ni = 0; ni < 2; ++ni) acc[mi][ni] = (f32x16)(0.0f);

  // Phase: kq pair p -> kq = 2p, 2p+1. 12 ds_read_b128 + staging -> bar -> 16 MFMA.
#define PHASE2(Ap, Bp, p, ...)                                                 \
  {                                                                            \
    bf16x8 af[4][2], bfr[2][2];                                                \
    _Pragma("unroll") for (int mi = 0; mi < 4; ++mi)                           \
        _Pragma("unroll") for (int q = 0; q < 2; ++q)                          \
            af[mi][q] = *(const bf16x8*)((Ap) + arow0 + mi * 4096 +            \
                (((2 * (p) + q) * 32 + g32 * 16) ^ swz));                      \
    _Pragma("unroll") for (int ni = 0; ni < 2; ++ni)                           \
        _Pragma("unroll") for (int q = 0; q < 2; ++q)                          \
            bfr[ni][q] = *(const bf16x8*)((Bp) + brow0 + ni * 4096 +           \
                (((2 * (p) + q) * 32 + g32 * 16) ^ swz));                      \
    __VA_ARGS__;                                                               \
    __builtin_amdgcn_s_barrier();                                              \
    __builtin_amdgcn_s_setprio(1);                                             \
    _Pragma("unroll") for (int mi = 0; mi < 4; ++mi)                           \
        _Pragma("unroll") for (int ni = 0; ni < 2; ++ni)                       \
            _Pragma("unroll") for (int q = 0; q < 2; ++q)                      \
                acc[mi][ni] = __builtin_amdgcn_mfma_f32_32x32x16_bf16(         \
                    af[mi][q], bfr[ni][q], acc[mi][ni], 0, 0, 0);              \
    __builtin_amdgcn_s_setprio(0);                                             \
  }

#define WAIT_BAR(n)                                                            \
  asm volatile("s_waitcnt vmcnt(" #n ") lgkmcnt(0)" ::: "memory");             \
  __builtin_amdgcn_s_barrier();                                                \
  __builtin_amdgcn_sched_barrier(0);

  // ---- prologue: tile 0 staged, A(1) loads in flight ----
  ALOADS(0);
  AWRITES(0);                    // compiler vmcnt-waits arA's loads
  STAGE_B(0, 0);                 // 4 gloads
  ALOADS(1);                     // 8 loads, stay in flight across the barrier
  __builtin_amdgcn_sched_barrier(0);
  WAIT_BAR(8);                   // drains B(0); leaves A(1)'s 8

  // ---- main loop: 2 phases per K-tile ----
#pragma unroll 1
  for (int kt = 0; kt < NKT; ++kt) {
    const int c = kt & 1;
    const char* Ap = (const char*)As[c];
    const char* Bp = (const char*)Bs[c];
    const int last = (kt == NKT - 1);

    // ph0: kq0,1 | stage next B
    PHASE2(Ap, Bp, 0, if (!last) STAGE_B(kt + 1, c ^ 1));
    __builtin_amdgcn_s_barrier();
    // ph1: kq2,3 | write next A (loads 2 phases old), issue A(kt+2)
    PHASE2(Ap, Bp, 1,
           if (!last) {
             AWRITES(c ^ 1);
             if (kt + 2 < NKT) ALOADS(kt + 2);
           });
    if (kt + 2 < NKT) { WAIT_BAR(8); } else { WAIT_BAR(0); }
  }

  // ---- fused top-4: each wave owns one 128-row chunk (wm), cols wn*64..+63 ----
  // C frag (32x32): col = l32, row = (r&3) + 8*(r>>2) + 4*g32 (+ mi*32).
  // In-lane: 4 row-groups of 4 per mi; cross-half merge via shfl_xor(32).
  const int mchunk = mtile * 2 + wm;      // global 128-row chunk id
  const int b = mchunk >> 5;
  const int chunk = mchunk & 31;
#pragma unroll
  for (int ni = 0; ni < 2; ++ni) {
    float a0, a1, a2, a3;
    {
      a0 = acc[0][ni][0]; a1 = acc[0][ni][1]; a2 = acc[0][ni][2]; a3 = acc[0][ni][3];
      sort4(a0, a1, a2, a3);
    }
#pragma unroll
    for (int mi = 0; mi < 4; ++mi)
#pragma unroll
      for (int gq = 0; gq < 4; ++gq) {
        if (mi == 0 && gq == 0) continue;
        float b0 = acc[mi][ni][gq * 4 + 0], b1 = acc[mi][ni][gq * 4 + 1];
        float b2 = acc[mi][ni][gq * 4 + 2], b3 = acc[mi][ni][gq * 4 + 3];
        sort4(b0, b1, b2, b3);
        merge4(a0, a1, a2, a3, b0, b1, b2, b3);
      }
    {
      float e0 = __shfl_xor(a0, 32), e1 = __shfl_xor(a1, 32);
      float e2 = __shfl_xor(a2, 32), e3 = __shfl_xor(a3, 32);
      merge4(a0, a1, a2, a3, e0, e1, e2, e3);
    }
    if (lane < 32) {
      const int f = n0 + wn * 64 + ni * 32 + l32;
      float4 v; v.x = a0; v.y = a1; v.z = a2; v.w = a3;
      *(float4*)(cand + (((size_t)(b * FDIM + f)) * NCHUNK + chunk) * 4) = v;
    }
  }
}

// ---------------------- merge 32 chunk-lists + 4-term contraction + relu -> out
// one wave per output row (b,ff); 4 rows per block
__global__ __launch_bounds__(256) void out_kernel(
    const float* __restrict__ cand, const float* __restrict__ R,
    const float* __restrict__ Bb, float* __restrict__ out) {
  const int row = blockIdx.x * 4 + (threadIdx.x >> 6);  // b*512 + ff
  const int lane = threadIdx.x & 63;
  const int b = row >> 9, ff = row & 511;
  const int m2 = ff & 127;

  const float4 cv = *(const float4*)(cand +
      (((size_t)(b * FDIM + ff)) * NCHUNK + (lane & 31)) * 4);
  float t0 = cv.x, t1 = cv.y, t2 = cv.z, t3 = cv.w;
#pragma unroll
  for (int off = 1; off < 32; off <<= 1) {
    float e0 = __shfl_xor(t0, off), e1 = __shfl_xor(t1, off);
    float e2 = __shfl_xor(t2, off), e3 = __shfl_xor(t3, off);
    merge4(t0, t1, t2, t3, e0, e1, e2, e3);
  }
  t0 = fmaxf(t0, 0.f); t1 = fmaxf(t1, 0.f); t2 = fmaxf(t2, 0.f); t3 = fmaxf(t3, 0.f);

  const float* R0 = R + (size_t)(4 * m2) * FDIM;
  const float* Bbr = Bb + (size_t)m2 * FDIM;
  float* ob = out + (size_t)row * FDIM;
#pragma unroll
  for (int jq = 0; jq < 8; ++jq) {
    const int q = jq * 64 + lane;
    float s = Bbr[q];
    s = fmaf(t0, R0[q], s);
    s = fmaf(t1, R0[FDIM + q], s);
    s = fmaf(t2, R0[2 * FDIM + q], s);
    s = fmaf(t3, R0[3 * FDIM + q], s);
    ob[q] = s > 0.f ? s : 0.f;
  }
}

// ---------------------------------------------------------------------------------
extern "C" void kernel_launch(void* const* d_in, const int* in_sizes, int n_in,
                              void* d_out, int out_size, void* d_ws, size_t ws_size,
                              hipStream_t stream) {
  const float* x  = (const float*)d_in[0];
  const float* Wu = (const float*)d_in[1];
  const float* P  = (const float*)d_in[2];
  const float* Q  = (const float*)d_in[3];
  const float* Bb = (const float*)d_in[4];
  float* out = (float*)d_out;

  char* ws = (char*)d_ws;
  unsigned short* wuT = (unsigned short*)(ws);          //  524288 B
  float*          R   = (float*)(ws + 524288L);         // 1048576 B
  float*          cand= (float*)(ws + 1572864L);        // 8388608 B

  hipLaunchKernelGGL(cvt_wuT_kernel, dim3(512), dim3(256), 0, stream, Wu, wuT);
  hipLaunchKernelGGL(compute_R_kernel, dim3(2, 512), dim3(256), 0, stream, P, Q, R);
  hipLaunchKernelGGL(gemm_topk_kernel, dim3(1024), dim3(512), 0, stream, x, wuT, cand);
  hipLaunchKernelGGL(out_kernel, dim3(BSZ * FDIM / 4), dim3(256), 0, stream, cand, R, Bb, out);
}